// Round 12
// baseline (181.243 us; speedup 1.0000x reference)
//
#include <hip/hip_runtime.h>

// ---------- types ----------
typedef _Float16 f16x8 __attribute__((ext_vector_type(8)));
typedef _Float16 f16x4 __attribute__((ext_vector_type(4)));
typedef _Float16 f16x2 __attribute__((ext_vector_type(2)));
typedef float f32x4 __attribute__((ext_vector_type(4)));
typedef unsigned int u32x4 __attribute__((ext_vector_type(4)));

// rho: global key row -> permuted row within 128-row K-tile (32-key groups kept)
#define RHO(s) (((s) & ~31) | (((s) >> 2) & 1) * 16 | (((s) >> 3) & 3) * 4 | ((s) & 3))

__device__ __forceinline__ float fexp2(float x) {
#if __has_builtin(__builtin_amdgcn_exp2f)
    return __builtin_amdgcn_exp2f(x);
#else
    return exp2f(x);
#endif
}
__device__ __forceinline__ f16x4 pack_f16x4(float a, float b, float c, float d) {
    f16x4 r;
    r[0] = (_Float16)a; r[1] = (_Float16)b;
    r[2] = (_Float16)c; r[3] = (_Float16)d;
    return r;
}
// packed RTZ convert: 2 floats -> 2 halves in one VALU op (P-matrix only)
__device__ __forceinline__ f16x4 pack_pk(float a, float b, float c, float d) {
#if __has_builtin(__builtin_amdgcn_cvt_pkrtz)
    f16x2 lo = __builtin_bit_cast(f16x2, __builtin_amdgcn_cvt_pkrtz(a, b));
    f16x2 hi = __builtin_bit_cast(f16x2, __builtin_amdgcn_cvt_pkrtz(c, d));
    f16x4 r;
    r[0] = lo[0]; r[1] = lo[1]; r[2] = hi[0]; r[3] = hi[1];
    return r;
#else
    return pack_f16x4(a, b, c, d);
#endif
}
__device__ __forceinline__ f16x8 cat_f16x8(f16x4 a, f16x4 b) {
    f16x8 r;
    for (int i = 0; i < 4; ++i) { r[i] = a[i]; r[4 + i] = b[i]; }
    return r;
}

// async global->LDS, 16B per lane; lds dest = wave-uniform base + lane*16
__device__ __forceinline__ void gld16(const void* g, void* l) {
#if __has_builtin(__builtin_amdgcn_global_load_lds)
    __builtin_amdgcn_global_load_lds(
        (const __attribute__((address_space(1))) void*)(unsigned long long)g,
        (__attribute__((address_space(3))) void*)(unsigned int)(unsigned long long)l,
        16, 0, 0);
#else
    *(u32x4*)l = *(const u32x4*)g;
#endif
}

// ---------- convert f32 -> fp16 (x + 4 weights in one launch) ----------
__global__ __launch_bounds__(256) void cvt_all_kernel(
    const float* __restrict__ x, const float* __restrict__ wq,
    const float* __restrict__ wk, const float* __restrict__ wv,
    const float* __restrict__ wo,
    _Float16* __restrict__ xh, _Float16* __restrict__ wqkvh,
    _Float16* __restrict__ woh)
{
    long i = (long)blockIdx.x * 256 + threadIdx.x;  // float4 index, 2M total
    const float* src; _Float16* dst; long off;
    if (i < 1048576)      { src = x;  dst = xh;              off = i; }
    else if (i < 1310720) { src = wq; dst = wqkvh;           off = i - 1048576; }
    else if (i < 1572864) { src = wk; dst = wqkvh + 1048576; off = i - 1310720; }
    else if (i < 1835008) { src = wv; dst = wqkvh + 2097152; off = i - 1572864; }
    else                  { src = wo; dst = woh;             off = i - 1835008; }
    float4 v = ((const float4*)src)[off];
    *(f16x4*)&dst[off * 4] = pack_f16x4(v.x, v.y, v.z, v.w);
}

// ---------- QKV GEMM: C = A @ B^T, 128x128 tile, BK=32, ring-4 LDS pipeline ----
// 256 threads (4 waves, 2Mx2N, acc[4][4], 16 MFMA/iter), LDS ring-4 = 64 KB ->
// 2 blocks/CU; grid 32x24=768 fills all residency slots. Counted vmcnt(8).
// T2 slot-swizzle (R8: conflicts 2.36M -> 0).
// Epilogue: Q -> qb [bh][s][64] (pre-scaled log2e/8); K -> kb attn-image blobs;
// V -> vb 64-key subtile blobs (subtile = kt0*2 + wm).
__global__ __launch_bounds__(256, 2) void gemm128_qkv(
    const _Float16* __restrict__ A, const _Float16* __restrict__ B,
    _Float16* __restrict__ qb, _Float16* __restrict__ kb2,
    _Float16* __restrict__ vb)
{
    constexpr int K = 1024;
    constexpr int NT = 32;  // K / 32
    __shared__ __align__(16) _Float16 smem[4 * 8192];  // 64 KB ring

    const int tid = threadIdx.x;
    const int wave = tid >> 6, lane = tid & 63;
    const int quad = lane >> 4, l16 = lane & 15;
    const int bm = blockIdx.x, bn = blockIdx.y;
    const int wm = wave >> 1;  // 0..1 : M half (64 rows)
    const int wn = wave & 1;   // 0..1 : N half (64 cols)

    const int arow0 = bm * 128, brow0 = bn * 128;

    const int c0 = tid, c1 = 256 + tid;
    const int r0 = c0 >> 2, k80 = ((c0 & 3) ^ ((c0 >> 3) & 3)) * 8;
    const int r1 = c1 >> 2, k81 = ((c1 & 3) ^ ((c1 >> 3) & 3)) * 8;
    const int rsw = (l16 >> 1) & 3;  // read-side slot mask (row terms 0 mod 4)

    f32x4 zero = {0.f, 0.f, 0.f, 0.f};
    f32x4 acc[4][4];
    for (int i = 0; i < 4; i++) for (int j = 0; j < 4; j++) acc[i][j] = zero;

#define STAGE(t) { \
    _Float16* sA_ = smem + ((t) & 3) * 8192; \
    _Float16* sB_ = sA_ + 4096; \
    const _Float16* ga_ = A + (long)arow0 * K + (t) * 32; \
    const _Float16* gb_ = B + (long)brow0 * K + (t) * 32; \
    gld16(&ga_[(long)r0 * K + k80], &sA_[c0 * 8]); \
    gld16(&ga_[(long)r1 * K + k81], &sA_[c1 * 8]); \
    gld16(&gb_[(long)r0 * K + k80], &sB_[c0 * 8]); \
    gld16(&gb_[(long)r1 * K + k81], &sB_[c1 * 8]); \
}

    STAGE(0);
    STAGE(1);

    for (int t = 0; t < NT; ++t) {
        if (t + 2 < NT) {
            STAGE(t + 2);
            asm volatile("s_waitcnt vmcnt(8)" ::: "memory");   // tile t landed
        } else if (t + 1 < NT) {
            asm volatile("s_waitcnt vmcnt(4)" ::: "memory");   // tile t landed
        } else {
            asm volatile("s_waitcnt vmcnt(0)" ::: "memory");
        }
        __builtin_amdgcn_s_barrier();

        const _Float16* sA = smem + (t & 3) * 8192;
        const _Float16* sB = sA + 4096;
        f16x8 af[4], bf[4];
#pragma unroll
        for (int n = 0; n < 4; ++n)
            bf[n] = *(const f16x8*)&sB[(wn * 64 + n * 16 + l16) * 32 +
                                       ((quad ^ rsw) * 8)];
#pragma unroll
        for (int m = 0; m < 4; ++m)
            af[m] = *(const f16x8*)&sA[(wm * 64 + m * 16 + l16) * 32 +
                                       ((quad ^ rsw) * 8)];
        __builtin_amdgcn_s_setprio(1);
#pragma unroll
        for (int m = 0; m < 4; ++m)
#pragma unroll
            for (int n = 0; n < 4; ++n)
                acc[m][n] = __builtin_amdgcn_mfma_f32_16x16x32_f16(af[m], bf[n], acc[m][n], 0, 0, 0);
        __builtin_amdgcn_s_setprio(0);
    }
#undef STAGE

    // ---- epilogue ----
    const int p = bn >> 3;
    const int h = (bn & 7) * 2 + wn;
    const int b = bm >> 4;
    const int kt0 = bm & 15;
    const float QSCALE = 0.18033688011112042f;  // log2(e)/8 -> exp2-domain softmax

    if (p == 0) {
        const long base = ((long)(b * 16 + h)) * 2048;
        for (int m = 0; m < 4; ++m) {
            for (int n = 0; n < 4; ++n) {
                int dd = n * 16 + l16;
                for (int r = 0; r < 4; ++r) {
                    long s = kt0 * 128 + wm * 64 + m * 16 + quad * 4 + r;
                    qb[(base + s) * 64 + dd] = (_Float16)(acc[m][n][r] * QSCALE);
                }
            }
        }
    } else if (p == 1) {
        _Float16* dstt = kb2 + ((long)(b * 16 + h) * 16 + kt0) * 8192;
        for (int m = 0; m < 4; ++m) {
            for (int n = 0; n < 4; ++n) {
                int dd = n * 16 + l16;
                int ch = dd >> 3, dl = dd & 7;
                for (int r = 0; r < 4; ++r) {
                    int rk = wm * 64 + m * 16 + quad * 4 + r;
                    int pr = RHO(rk);
                    dstt[pr * 64 + ((ch ^ (pr & 7)) << 3) + dl] = (_Float16)acc[m][n][r];
                }
            }
        }
    } else {
        // V 64-key subtile image: subtile = kt0*2 + wm
        _Float16* dstt = vb + (((long)(b * 16 + h) * 16 + kt0) * 2 + wm) * 4096;
        for (int m = 0; m < 4; ++m) {
            int c0v = m * 16 + quad * 4;  // key col within the 64-key subtile
            for (int n = 0; n < 4; ++n) {
                int dd = n * 16 + l16;
                int voff = dd * 64 + (((c0v >> 3) ^ (dd & 7)) << 3) + (c0v & 7);
                *(f16x4*)&dstt[voff] = pack_f16x4(acc[m][n][0], acc[m][n][1],
                                                  acc[m][n][2], acc[m][n][3]);
            }
        }
    }
}

// ---------- out-proj GEMM: C = A @ B^T, 128x128 tile, BK=32, ring-4, fp32 out ----
__global__ __launch_bounds__(256, 2) void gemm128_out(
    const _Float16* __restrict__ A, const _Float16* __restrict__ B,
    float* __restrict__ outf)
{
    constexpr int K = 1024;
    constexpr int NT = 32;  // K / 32
    __shared__ __align__(16) _Float16 smem[4 * 8192];  // 64 KB ring

    const int tid = threadIdx.x;
    const int wave = tid >> 6, lane = tid & 63;
    const int quad = lane >> 4, l16 = lane & 15;
    const int bm = blockIdx.x, bn = blockIdx.y;
    const int wm = wave >> 1;
    const int wn = wave & 1;

    const int arow0 = bm * 128, brow0 = bn * 128;

    const int c0 = tid, c1 = 256 + tid;
    const int r0 = c0 >> 2, k80 = ((c0 & 3) ^ ((c0 >> 3) & 3)) * 8;
    const int r1 = c1 >> 2, k81 = ((c1 & 3) ^ ((c1 >> 3) & 3)) * 8;
    const int rsw = (l16 >> 1) & 3;

    f32x4 zero = {0.f, 0.f, 0.f, 0.f};
    f32x4 acc[4][4];
    for (int i = 0; i < 4; i++) for (int j = 0; j < 4; j++) acc[i][j] = zero;

#define STAGE(t) { \
    _Float16* sA_ = smem + ((t) & 3) * 8192; \
    _Float16* sB_ = sA_ + 4096; \
    const _Float16* ga_ = A + (long)arow0 * K + (t) * 32; \
    const _Float16* gb_ = B + (long)brow0 * K + (t) * 32; \
    gld16(&ga_[(long)r0 * K + k80], &sA_[c0 * 8]); \
    gld16(&ga_[(long)r1 * K + k81], &sA_[c1 * 8]); \
    gld16(&gb_[(long)r0 * K + k80], &sB_[c0 * 8]); \
    gld16(&gb_[(long)r1 * K + k81], &sB_[c1 * 8]); \
}

    STAGE(0);
    STAGE(1);

    for (int t = 0; t < NT; ++t) {
        if (t + 2 < NT) {
            STAGE(t + 2);
            asm volatile("s_waitcnt vmcnt(8)" ::: "memory");
        } else if (t + 1 < NT) {
            asm volatile("s_waitcnt vmcnt(4)" ::: "memory");
        } else {
            asm volatile("s_waitcnt vmcnt(0)" ::: "memory");
        }
        __builtin_amdgcn_s_barrier();

        const _Float16* sA = smem + (t & 3) * 8192;
        const _Float16* sB = sA + 4096;
        f16x8 af[4], bf[4];
#pragma unroll
        for (int n = 0; n < 4; ++n)
            bf[n] = *(const f16x8*)&sB[(wn * 64 + n * 16 + l16) * 32 +
                                       ((quad ^ rsw) * 8)];
#pragma unroll
        for (int m = 0; m < 4; ++m)
            af[m] = *(const f16x8*)&sA[(wm * 64 + m * 16 + l16) * 32 +
                                       ((quad ^ rsw) * 8)];
        __builtin_amdgcn_s_setprio(1);
#pragma unroll
        for (int m = 0; m < 4; ++m)
#pragma unroll
            for (int n = 0; n < 4; ++n)
                acc[m][n] = __builtin_amdgcn_mfma_f32_16x16x32_f16(af[m], bf[n], acc[m][n], 0, 0, 0);
        __builtin_amdgcn_s_setprio(0);
    }
#undef STAGE

    for (int m = 0; m < 4; ++m) {
        int row = bm * 128 + wm * 64 + m * 16 + quad * 4;
        for (int n = 0; n < 4; ++n) {
            int col = bn * 128 + wn * 64 + n * 16 + l16;
            for (int r = 0; r < 4; ++r)
                outf[(long)(row + r) * 1024 + col] = acc[m][n][r];
        }
    }
}

// ---------- flash attention v16: tile-PAIR interleave (T15) over ring-4 ----------
// R11 showed the barrier drain was NOT attn's stall (counted vmcnt = flat);
// MfmaUtil 31% == serial QK->exp2->PV chain with only 2 waves/SIMD. v16 keeps
// v15's ring-4 + counted vmcnt but processes TWO tiles per iteration, ordered
//   QK(a); QK(b); exp2(a); [PV(a) || exp2(b)]; PV(b)
// so exp2(a) no longer stalls on QK(a) result latency (QK(b)'s MFMAs cover it)
// and exp2(b)'s VALU issues under PV(a)'s matrix-pipe occupancy. Barriers halve.
// vmcnt: stage 2 tiles/iter (8 loads); steady wait vmcnt(8) -> pair landed.
// Slot safety: STAGE(p+2/p+3) touch slots (p+2)&3,(p+3)&3 != (p)&3,(p+1)&3 being
// read; post-barrier skewed STAGE(p+4) hits slot p&3, which all waves finished
// reading BEFORE the barrier. One barrier per pair iter.
__global__ __launch_bounds__(256, 2) void attn_kernel(
    const _Float16* __restrict__ qb, const _Float16* __restrict__ kb,
    const _Float16* __restrict__ vt, _Float16* __restrict__ ob)
{
    constexpr int S = 2048;
    constexpr int SLOT = 8192;                         // halves: K 4096 | V 4096
    __shared__ __align__(16) _Float16 smem[4 * SLOT];  // 64 KB ring

    const int tid = threadIdx.x, wave = tid >> 6, lane = tid & 63;
    const int quad = lane >> 4, l16 = lane & 15;
    const int sw = l16 & 7;
    // XCD-pinned decode (round-robin dispatch heuristic; correctness-independent)
    const int n = blockIdx.x;
    const int qt = (n >> 3) & 15;
    const int bh = (n & 7) | ((n >> 7) << 3);

    // Q frags (B-operand of 16x16x32), two q-groups
    const _Float16* qrow = qb + (((long)bh * S) + qt * 128 + wave * 32 + l16) * 64;
    f16x8 qf00 = *(const f16x8*)&qrow[quad * 8];
    f16x8 qf01 = *(const f16x8*)&qrow[32 + quad * 8];
    f16x8 qf10 = *(const f16x8*)&qrow[16 * 64 + quad * 8];
    f16x8 qf11 = *(const f16x8*)&qrow[16 * 64 + 32 + quad * 8];

    const _Float16* kg = kb + (long)bh * 32 * 4096;  // 8 KB 64-key subtile blobs
    const _Float16* vg = vt + (long)bh * 32 * 4096;

    float l0 = 0.f, l1 = 0.f;
    f32x4 zero = {0.f, 0.f, 0.f, 0.f};
    f32x4 oa0[4], oa1[4];  // D[m=q=quad*4+r][n=d=l16], dg blocks of 16 d
    for (int d = 0; d < 4; d++) { oa0[d] = zero; oa1[d] = zero; }

    // linear blob -> linear LDS, 16 B/lane; thread t copies chunks t + j*256
#define STAGE_ATT(t) { \
    const _Float16* gk_ = kg + (long)(t) * 4096; \
    const _Float16* gv_ = vg + (long)(t) * 4096; \
    _Float16* sk_ = smem + ((t) & 3) * SLOT; \
    _Float16* sv_ = sk_ + 4096; \
    for (int j = 0; j < 2; ++j) { \
        gld16(&gk_[(tid + j * 256) * 8], &sk_[(tid + j * 256) * 8]); \
        gld16(&gv_[(tid + j * 256) * 8], &sv_[(tid + j * 256) * 8]); \
    } \
}

// QK phase for one tile: 8 chained-pair MFMAs -> sc0/sc1[4]
#define QK(sK, sc0v, sc1v) { \
    _Pragma("unroll") \
    for (int m = 0; m < 4; ++m) { \
        const _Float16* kr = &(sK)[(m * 16 + l16) * 64]; \
        f16x8 kf0 = *(const f16x8*)&kr[((quad)     ^ sw) * 8]; \
        f16x8 kf1 = *(const f16x8*)&kr[((quad + 4) ^ sw) * 8]; \
        f32x4 s0 = __builtin_amdgcn_mfma_f32_16x16x32_f16(kf0, qf00, zero, 0, 0, 0); \
        sc0v[m] = __builtin_amdgcn_mfma_f32_16x16x32_f16(kf1, qf01, s0, 0, 0, 0); \
        f32x4 s1 = __builtin_amdgcn_mfma_f32_16x16x32_f16(kf0, qf10, zero, 0, 0, 0); \
        sc1v[m] = __builtin_amdgcn_mfma_f32_16x16x32_f16(kf1, qf11, s1, 0, 0, 0); \
    } \
}

// exp2 + lane-local l + pack P frags for one tile
#define SOFTMAX(sc0v, sc1v, pf0v, pf1v) { \
    _Pragma("unroll") \
    for (int m = 0; m < 4; ++m) { \
        float a0 = fexp2(sc0v[m][0]), a1 = fexp2(sc0v[m][1]); \
        float a2 = fexp2(sc0v[m][2]), a3 = fexp2(sc0v[m][3]); \
        l0 += (a0 + a1) + (a2 + a3); \
        pf0v[m] = pack_pk(a0, a1, a2, a3); \
        float b0 = fexp2(sc1v[m][0]), b1 = fexp2(sc1v[m][1]); \
        float b2 = fexp2(sc1v[m][2]), b3 = fexp2(sc1v[m][3]); \
        l1 += (b0 + b1) + (b2 + b3); \
        pf1v[m] = pack_pk(b0, b1, b2, b3); \
    } \
}

// PV phase for one tile
#define PV(sVT, pf0v, pf1v) { \
    _Pragma("unroll") \
    for (int g = 0; g < 2; ++g) { \
        f16x8 a0 = cat_f16x8(pf0v[2 * g], pf0v[2 * g + 1]); \
        f16x8 a1 = cat_f16x8(pf1v[2 * g], pf1v[2 * g + 1]); \
        _Pragma("unroll") \
        for (int dg = 0; dg < 4; ++dg) { \
            f16x8 vf = *(const f16x8*)&(sVT)[(dg * 16 + l16) * 64 + \
                                             (((4 * g + quad) ^ sw) * 8)]; \
            oa0[dg] = __builtin_amdgcn_mfma_f32_16x16x32_f16(a0, vf, oa0[dg], 0, 0, 0); \
            oa1[dg] = __builtin_amdgcn_mfma_f32_16x16x32_f16(a1, vf, oa1[dg], 0, 0, 0); \
        } \
    } \
}

    STAGE_ATT(0);
    STAGE_ATT(1);

    for (int kt = 0; kt < 32; kt += 2) {
        if (kt + 2 < 32) {
            STAGE_ATT(kt + 2);
            STAGE_ATT(kt + 3);
            asm volatile("s_waitcnt vmcnt(8)" ::: "memory");   // pair kt,kt+1 landed
        } else {
            asm volatile("s_waitcnt vmcnt(0)" ::: "memory");
        }
        __builtin_amdgcn_s_barrier();

        const _Float16* sKa  = smem + (kt & 3) * SLOT;
        const _Float16* sVTa = sKa + 4096;
        const _Float16* sKb  = smem + ((kt + 1) & 3) * SLOT;
        const _Float16* sVTb = sKb + 4096;

        f32x4 sc0a[4], sc1a[4], sc0b[4], sc1b[4];
        f16x4 pf0a[4], pf1a[4], pf0b[4], pf1b[4];

        // QK(a); QK(b) back-to-back: 16 independent MFMA chains fill the pipe
        __builtin_amdgcn_s_setprio(1);
        QK(sKa, sc0a, sc1a);
        QK(sKb, sc0b, sc1b);
        __builtin_amdgcn_s_setprio(0);

        // exp2(a): QK(a) results are long since ready (QK(b) covered the latency)
        SOFTMAX(sc0a, sc1a, pf0a, pf1a);

        // PV(a) with exp2(b) in the same scheduling region: exp2(b)'s VALU has no
        // dependency on PV(a) -> issues under PV(a)'s matrix-pipe occupancy
        __builtin_amdgcn_s_setprio(1);
        PV(sVTa, pf0a, pf1a);
        SOFTMAX(sc0b, sc1b, pf0b, pf1b);
        PV(sVTb, pf0b, pf1b);
        __builtin_amdgcn_s_setprio(0);
    }
#undef STAGE_ATT
#undef QK
#undef SOFTMAX
#undef PV

    // epilogue: reduce l across quads, normalize, store fp16 O [t][1024]
    const int b = bh >> 4, h = bh & 15;
    for (int g = 0; g < 2; ++g) {
        float lr = (g == 0) ? l0 : l1;
        lr += __shfl_xor(lr, 16);
        lr += __shfl_xor(lr, 32);           // every lane: l(q = its l16) for group g
        float linv[4];
        for (int r = 0; r < 4; ++r)
            linv[r] = 1.f / __shfl(lr, quad * 4 + r);  // l for q = quad*4+r
        f32x4* oa = (g == 0) ? oa0 : oa1;
        long t0 = (long)b * S + qt * 128 + wave * 32 + g * 16;
        for (int dg = 0; dg < 4; ++dg) {
            int col = h * 64 + dg * 16 + l16;
            for (int r = 0; r < 4; ++r) {
                long idx = (t0 + quad * 4 + r) * 1024 + col;
                ob[idx] = (_Float16)(oa[dg][r] * linv[r]);
            }
        }
    }
}

// ---------- launch ----------
extern "C" void kernel_launch(void* const* d_in, const int* in_sizes, int n_in,
                              void* d_out, int out_size, void* d_ws, size_t ws_size,
                              hipStream_t stream)
{
    const float* x  = (const float*)d_in[0];
    // d_in[1] = e (unused by reference)
    const float* wq = (const float*)d_in[2];
    const float* wk = (const float*)d_in[3];
    const float* wv = (const float*)d_in[4];
    const float* wo = (const float*)d_in[5];
    float* out = (float*)d_out;

    const size_t MT = 4096UL * 1024UL;
    const size_t WT = 1024UL * 1024UL;
    _Float16* xh    = (_Float16*)d_ws;  // [4096][1024]
    _Float16* wqkvh = xh + MT;          // [3072][1024]
    _Float16* woh   = wqkvh + 3 * WT;   // [1024][1024]
    _Float16* qbuf  = woh + WT;         // [32][2048][64] (pre-scaled by log2e/8)
    _Float16* kbuf  = qbuf + MT;        // [32][32][4096] K subtile blobs (attn image)
    _Float16* vbuf  = kbuf + MT;        // [32][32][4096] V subtile blobs (attn image)
    _Float16* obuf  = vbuf + MT;        // [4096][1024]
    // total 24M halves = 48 MB of workspace

    cvt_all_kernel<<<8192, 256, 0, stream>>>(x, wq, wk, wv, wo, xh, wqkvh, woh);

    gemm128_qkv<<<dim3(32, 24), 256, 0, stream>>>(xh, wqkvh, qbuf, kbuf, vbuf);
    attn_kernel<<<512, 256, 0, stream>>>(qbuf, kbuf, vbuf, obuf);
    gemm128_out<<<dim3(32, 8), 256, 0, stream>>>(obuf, woh, out);
}

// Round 13
// 179.243 us; speedup vs baseline: 1.0112x; 1.0112x over previous
//
#include <hip/hip_runtime.h>

// ---------- types ----------
typedef _Float16 f16x8 __attribute__((ext_vector_type(8)));
typedef _Float16 f16x4 __attribute__((ext_vector_type(4)));
typedef _Float16 f16x2 __attribute__((ext_vector_type(2)));
typedef float f32x4 __attribute__((ext_vector_type(4)));
typedef unsigned int u32x4 __attribute__((ext_vector_type(4)));

// rho: global key row -> permuted row within 128-row K-tile (32-key groups kept)
#define RHO(s) (((s) & ~31) | (((s) >> 2) & 1) * 16 | (((s) >> 3) & 3) * 4 | ((s) & 3))

__device__ __forceinline__ float fexp2(float x) {
#if __has_builtin(__builtin_amdgcn_exp2f)
    return __builtin_amdgcn_exp2f(x);
#else
    return exp2f(x);
#endif
}
__device__ __forceinline__ f16x4 pack_f16x4(float a, float b, float c, float d) {
    f16x4 r;
    r[0] = (_Float16)a; r[1] = (_Float16)b;
    r[2] = (_Float16)c; r[3] = (_Float16)d;
    return r;
}
// packed RTZ convert: 2 floats -> 2 halves in one VALU op (P-matrix only)
__device__ __forceinline__ f16x4 pack_pk(float a, float b, float c, float d) {
#if __has_builtin(__builtin_amdgcn_cvt_pkrtz)
    f16x2 lo = __builtin_bit_cast(f16x2, __builtin_amdgcn_cvt_pkrtz(a, b));
    f16x2 hi = __builtin_bit_cast(f16x2, __builtin_amdgcn_cvt_pkrtz(c, d));
    f16x4 r;
    r[0] = lo[0]; r[1] = lo[1]; r[2] = hi[0]; r[3] = hi[1];
    return r;
#else
    return pack_f16x4(a, b, c, d);
#endif
}
__device__ __forceinline__ f16x8 cat_f16x8(f16x4 a, f16x4 b) {
    f16x8 r;
    for (int i = 0; i < 4; ++i) { r[i] = a[i]; r[4 + i] = b[i]; }
    return r;
}

// async global->LDS, 16B per lane; lds dest = wave-uniform base + lane*16
__device__ __forceinline__ void gld16(const void* g, void* l) {
#if __has_builtin(__builtin_amdgcn_global_load_lds)
    __builtin_amdgcn_global_load_lds(
        (const __attribute__((address_space(1))) void*)(unsigned long long)g,
        (__attribute__((address_space(3))) void*)(unsigned int)(unsigned long long)l,
        16, 0, 0);
#else
    *(u32x4*)l = *(const u32x4*)g;
#endif
}

// ---------- convert f32 -> fp16 (x + 4 weights in one launch) ----------
__global__ __launch_bounds__(256) void cvt_all_kernel(
    const float* __restrict__ x, const float* __restrict__ wq,
    const float* __restrict__ wk, const float* __restrict__ wv,
    const float* __restrict__ wo,
    _Float16* __restrict__ xh, _Float16* __restrict__ wqkvh,
    _Float16* __restrict__ woh)
{
    long i = (long)blockIdx.x * 256 + threadIdx.x;  // float4 index, 2M total
    const float* src; _Float16* dst; long off;
    if (i < 1048576)      { src = x;  dst = xh;              off = i; }
    else if (i < 1310720) { src = wq; dst = wqkvh;           off = i - 1048576; }
    else if (i < 1572864) { src = wk; dst = wqkvh + 1048576; off = i - 1310720; }
    else if (i < 1835008) { src = wv; dst = wqkvh + 2097152; off = i - 1572864; }
    else                  { src = wo; dst = woh;             off = i - 1835008; }
    float4 v = ((const float4*)src)[off];
    *(f16x4*)&dst[off * 4] = pack_f16x4(v.x, v.y, v.z, v.w);
}

// ---------- QKV GEMM v2: 128x128 tile, 2 waves x (128x64), ring-2, BK=32 --------
// R12 analysis: the 4-wave 64x64-per-wave version was LDS-read-bound (per CU:
// 768 cyc ds_read vs 620 MFMA per K-step -- reads scale with (64+64)*BK vs FLOPs
// 64*64*BK). This version fattens the wave tile to 128x64 (acc[8][4]): 12 b128
// reads per 32 MFMA -> MFMA-bound. 128 threads (2 waves), ring-2 LDS double
// buffer = 32 KB -> 4 blocks/CU (__launch_bounds__(128,2)); grid 32x24 = 768 =
// exactly 3 blocks/CU. Counted vmcnt(8) (8 gld16/STAGE), two raw s_barriers per
// iter (pre-compute: loads landed; post-compute: slot free for next STAGE) --
// no vmcnt(0) drain in the loop.
// T2 slot-swizzle kept: source slot (c&3)^((c>>3)&3), read slot quad^((l16>>1)&3).
// Epilogue writes byte-identical blobs to the previous producer:
//   Q -> qb [bh][s][64] (pre-scaled log2e/8)
//   K -> kb blobs [bh][16 tiles][8192]: attn LDS image, off(rk,dd) =
//        RHO(rk)*64 + ((dd>>3 ^ (RHO(rk)&7))<<3) + (dd&7)  (64-key halves valid)
//   V -> vb blobs [bh][32 subtiles][4096]: off(dd,c) =
//        dd*64 + ((c>>3 ^ (dd&7))<<3) + (c&7); subtile = kt0*2 + (c0v>>6)
__global__ __launch_bounds__(128, 2) void gemm128_qkv(
    const _Float16* __restrict__ A, const _Float16* __restrict__ B,
    _Float16* __restrict__ qb, _Float16* __restrict__ kb2,
    _Float16* __restrict__ vb)
{
    constexpr int K = 1024;
    constexpr int NT = 32;  // K / 32
    __shared__ __align__(16) _Float16 smem[2 * 8192];  // 32 KB: 2 x (A 4096 | B 4096)

    const int tid = threadIdx.x;
    const int wave = tid >> 6, lane = tid & 63;
    const int quad = lane >> 4, l16 = lane & 15;
    const int bm = blockIdx.x, bn = blockIdx.y;
    const int wn = wave;  // 0..1 : N half (64 cols); wave spans all 128 rows

    const int arow0 = bm * 128, brow0 = bn * 128;

    // staging: tile = 512 chunks of 16B (128 rows x 4); thread covers chunks
    // tid + j*128, j=0..3, for A and B. Source slot XOR'd so the LDS image is
    // swizzled ((c>>3)&3 == (row>>1)&3 for the 4 chunks of a row).
    int cc[4], rr[4], kk[4];
#pragma unroll
    for (int j = 0; j < 4; ++j) {
        cc[j] = tid + j * 128;
        rr[j] = cc[j] >> 2;
        kk[j] = ((cc[j] & 3) ^ ((cc[j] >> 3) & 3)) * 8;
    }
    const int rsw = (l16 >> 1) & 3;  // read-side slot mask (row terms 0 mod 4)

    f32x4 zero = {0.f, 0.f, 0.f, 0.f};
    f32x4 acc[8][4];
    for (int m = 0; m < 8; m++) for (int n = 0; n < 4; n++) acc[m][n] = zero;

#define STAGE(t) { \
    _Float16* sA_ = smem + ((t) & 1) * 8192; \
    _Float16* sB_ = sA_ + 4096; \
    const _Float16* ga_ = A + (long)arow0 * K + (t) * 32; \
    const _Float16* gb_ = B + (long)brow0 * K + (t) * 32; \
    _Pragma("unroll") \
    for (int j = 0; j < 4; ++j) { \
        gld16(&ga_[(long)rr[j] * K + kk[j]], &sA_[cc[j] * 8]); \
        gld16(&gb_[(long)rr[j] * K + kk[j]], &sB_[cc[j] * 8]); \
    } \
}

    STAGE(0);

    for (int t = 0; t < NT; ++t) {
        if (t + 1 < NT) {
            STAGE(t + 1);
            asm volatile("s_waitcnt vmcnt(8)" ::: "memory");   // tile t landed
        } else {
            asm volatile("s_waitcnt vmcnt(0)" ::: "memory");
        }
        __builtin_amdgcn_s_barrier();   // all threads' tile-t loads visible

        const _Float16* sA = smem + (t & 1) * 8192;
        const _Float16* sB = sA + 4096;
        f16x8 af[8], bf[4];
#pragma unroll
        for (int n = 0; n < 4; ++n)
            bf[n] = *(const f16x8*)&sB[(wn * 64 + n * 16 + l16) * 32 +
                                       ((quad ^ rsw) * 8)];
#pragma unroll
        for (int m = 0; m < 8; ++m)
            af[m] = *(const f16x8*)&sA[(m * 16 + l16) * 32 + ((quad ^ rsw) * 8)];
        __builtin_amdgcn_s_setprio(1);
#pragma unroll
        for (int m = 0; m < 8; ++m)
#pragma unroll
            for (int n = 0; n < 4; ++n)
                acc[m][n] = __builtin_amdgcn_mfma_f32_16x16x32_f16(af[m], bf[n], acc[m][n], 0, 0, 0);
        __builtin_amdgcn_s_setprio(0);
        __builtin_amdgcn_s_barrier();   // slot t&1 free for STAGE(t+2) next iter
    }
#undef STAGE

    // ---- epilogue ----
    // p = bn>>3 (0=Q,1=K,2=V) block-uniform; head h = (bn&7)*2 + wn wave-uniform.
    // Rows: tile kt0 = bm&15, row within tile = m*16 + quad*4 + r (m=0..7).
    const int p = bn >> 3;
    const int h = (bn & 7) * 2 + wn;
    const int b = bm >> 4;
    const int kt0 = bm & 15;
    const float QSCALE = 0.18033688011112042f;  // log2(e)/8 -> exp2-domain softmax

    if (p == 0) {
        const long base = ((long)(b * 16 + h)) * 2048;
        for (int m = 0; m < 8; ++m) {
            for (int n = 0; n < 4; ++n) {
                int dd = n * 16 + l16;
                for (int r = 0; r < 4; ++r) {
                    long s = kt0 * 128 + m * 16 + quad * 4 + r;
                    qb[(base + s) * 64 + dd] = (_Float16)(acc[m][n][r] * QSCALE);
                }
            }
        }
    } else if (p == 1) {
        _Float16* dstt = kb2 + ((long)(b * 16 + h) * 16 + kt0) * 8192;
        for (int m = 0; m < 8; ++m) {
            for (int n = 0; n < 4; ++n) {
                int dd = n * 16 + l16;
                int ch = dd >> 3, dl = dd & 7;
                for (int r = 0; r < 4; ++r) {
                    int rk = m * 16 + quad * 4 + r;
                    int pr = RHO(rk);
                    dstt[pr * 64 + ((ch ^ (pr & 7)) << 3) + dl] = (_Float16)acc[m][n][r];
                }
            }
        }
    } else {
        // V 64-key subtile images: subtile = kt0*2 + (c0v>>6)
        _Float16* dstt = vb + ((long)(b * 16 + h) * 16 + kt0) * 8192;
        for (int m = 0; m < 8; ++m) {
            int c0v = m * 16 + quad * 4;       // key col within the 128-row tile
            int st = c0v >> 6, c = c0v & 63;   // subtile, col within subtile
            for (int n = 0; n < 4; ++n) {
                int dd = n * 16 + l16;
                int voff = st * 4096 + dd * 64 + (((c >> 3) ^ (dd & 7)) << 3) + (c & 7);
                *(f16x4*)&dstt[voff] = pack_f16x4(acc[m][n][0], acc[m][n][1],
                                                  acc[m][n][2], acc[m][n][3]);
            }
        }
    }
}

// ---------- out-proj GEMM: C = A @ B^T, 128x128 tile, BK=32, ring-4, fp32 out ----
__global__ __launch_bounds__(256, 2) void gemm128_out(
    const _Float16* __restrict__ A, const _Float16* __restrict__ B,
    float* __restrict__ outf)
{
    constexpr int K = 1024;
    constexpr int NT = 32;  // K / 32
    __shared__ __align__(16) _Float16 smem[4 * 8192];  // 64 KB ring

    const int tid = threadIdx.x;
    const int wave = tid >> 6, lane = tid & 63;
    const int quad = lane >> 4, l16 = lane & 15;
    const int bm = blockIdx.x, bn = blockIdx.y;
    const int wm = wave >> 1;
    const int wn = wave & 1;

    const int arow0 = bm * 128, brow0 = bn * 128;

    const int c0 = tid, c1 = 256 + tid;
    const int r0 = c0 >> 2, k80 = ((c0 & 3) ^ ((c0 >> 3) & 3)) * 8;
    const int r1 = c1 >> 2, k81 = ((c1 & 3) ^ ((c1 >> 3) & 3)) * 8;
    const int rsw = (l16 >> 1) & 3;

    f32x4 zero = {0.f, 0.f, 0.f, 0.f};
    f32x4 acc[4][4];
    for (int i = 0; i < 4; i++) for (int j = 0; j < 4; j++) acc[i][j] = zero;

#define STAGE(t) { \
    _Float16* sA_ = smem + ((t) & 3) * 8192; \
    _Float16* sB_ = sA_ + 4096; \
    const _Float16* ga_ = A + (long)arow0 * K + (t) * 32; \
    const _Float16* gb_ = B + (long)brow0 * K + (t) * 32; \
    gld16(&ga_[(long)r0 * K + k80], &sA_[c0 * 8]); \
    gld16(&ga_[(long)r1 * K + k81], &sA_[c1 * 8]); \
    gld16(&gb_[(long)r0 * K + k80], &sB_[c0 * 8]); \
    gld16(&gb_[(long)r1 * K + k81], &sB_[c1 * 8]); \
}

    STAGE(0);
    STAGE(1);

    for (int t = 0; t < NT; ++t) {
        if (t + 2 < NT) {
            STAGE(t + 2);
            asm volatile("s_waitcnt vmcnt(8)" ::: "memory");
        } else if (t + 1 < NT) {
            asm volatile("s_waitcnt vmcnt(4)" ::: "memory");
        } else {
            asm volatile("s_waitcnt vmcnt(0)" ::: "memory");
        }
        __builtin_amdgcn_s_barrier();

        const _Float16* sA = smem + (t & 3) * 8192;
        const _Float16* sB = sA + 4096;
        f16x8 af[4], bf[4];
#pragma unroll
        for (int n = 0; n < 4; ++n)
            bf[n] = *(const f16x8*)&sB[(wn * 64 + n * 16 + l16) * 32 +
                                       ((quad ^ rsw) * 8)];
#pragma unroll
        for (int m = 0; m < 4; ++m)
            af[m] = *(const f16x8*)&sA[(wm * 64 + m * 16 + l16) * 32 +
                                       ((quad ^ rsw) * 8)];
        __builtin_amdgcn_s_setprio(1);
#pragma unroll
        for (int m = 0; m < 4; ++m)
#pragma unroll
            for (int n = 0; n < 4; ++n)
                acc[m][n] = __builtin_amdgcn_mfma_f32_16x16x32_f16(af[m], bf[n], acc[m][n], 0, 0, 0);
        __builtin_amdgcn_s_setprio(0);
    }
#undef STAGE

    for (int m = 0; m < 4; ++m) {
        int row = bm * 128 + wm * 64 + m * 16 + quad * 4;
        for (int n = 0; n < 4; ++n) {
            int col = bn * 128 + wn * 64 + n * 16 + l16;
            for (int r = 0; r < 4; ++r)
                outf[(long)(row + r) * 1024 + col] = acc[m][n][r];
        }
    }
}

// ---------- flash attention v16: tile-PAIR interleave (T15) over ring-4 ----------
// Converged structure (R10-R12: drain-barrier / counted-vmcnt / pair-interleave
// all ~41.5 us). Kept as-is.
__global__ __launch_bounds__(256, 2) void attn_kernel(
    const _Float16* __restrict__ qb, const _Float16* __restrict__ kb,
    const _Float16* __restrict__ vt, _Float16* __restrict__ ob)
{
    constexpr int S = 2048;
    constexpr int SLOT = 8192;                         // halves: K 4096 | V 4096
    __shared__ __align__(16) _Float16 smem[4 * SLOT];  // 64 KB ring

    const int tid = threadIdx.x, wave = tid >> 6, lane = tid & 63;
    const int quad = lane >> 4, l16 = lane & 15;
    const int sw = l16 & 7;
    // XCD-pinned decode (round-robin dispatch heuristic; correctness-independent)
    const int n = blockIdx.x;
    const int qt = (n >> 3) & 15;
    const int bh = (n & 7) | ((n >> 7) << 3);

    // Q frags (B-operand of 16x16x32), two q-groups
    const _Float16* qrow = qb + (((long)bh * S) + qt * 128 + wave * 32 + l16) * 64;
    f16x8 qf00 = *(const f16x8*)&qrow[quad * 8];
    f16x8 qf01 = *(const f16x8*)&qrow[32 + quad * 8];
    f16x8 qf10 = *(const f16x8*)&qrow[16 * 64 + quad * 8];
    f16x8 qf11 = *(const f16x8*)&qrow[16 * 64 + 32 + quad * 8];

    const _Float16* kg = kb + (long)bh * 32 * 4096;  // 8 KB 64-key subtile blobs
    const _Float16* vg = vt + (long)bh * 32 * 4096;

    float l0 = 0.f, l1 = 0.f;
    f32x4 zero = {0.f, 0.f, 0.f, 0.f};
    f32x4 oa0[4], oa1[4];  // D[m=q=quad*4+r][n=d=l16], dg blocks of 16 d
    for (int d = 0; d < 4; d++) { oa0[d] = zero; oa1[d] = zero; }

    // linear blob -> linear LDS, 16 B/lane; thread t copies chunks t + j*256
#define STAGE_ATT(t) { \
    const _Float16* gk_ = kg + (long)(t) * 4096; \
    const _Float16* gv_ = vg + (long)(t) * 4096; \
    _Float16* sk_ = smem + ((t) & 3) * SLOT; \
    _Float16* sv_ = sk_ + 4096; \
    for (int j = 0; j < 2; ++j) { \
        gld16(&gk_[(tid + j * 256) * 8], &sk_[(tid + j * 256) * 8]); \
        gld16(&gv_[(tid + j * 256) * 8], &sv_[(tid + j * 256) * 8]); \
    } \
}

// QK phase for one tile: 8 chained-pair MFMAs -> sc0/sc1[4]
#define QK(sK, sc0v, sc1v) { \
    _Pragma("unroll") \
    for (int m = 0; m < 4; ++m) { \
        const _Float16* kr = &(sK)[(m * 16 + l16) * 64]; \
        f16x8 kf0 = *(const f16x8*)&kr[((quad)     ^ sw) * 8]; \
        f16x8 kf1 = *(const f16x8*)&kr[((quad + 4) ^ sw) * 8]; \
        f32x4 s0 = __builtin_amdgcn_mfma_f32_16x16x32_f16(kf0, qf00, zero, 0, 0, 0); \
        sc0v[m] = __builtin_amdgcn_mfma_f32_16x16x32_f16(kf1, qf01, s0, 0, 0, 0); \
        f32x4 s1 = __builtin_amdgcn_mfma_f32_16x16x32_f16(kf0, qf10, zero, 0, 0, 0); \
        sc1v[m] = __builtin_amdgcn_mfma_f32_16x16x32_f16(kf1, qf11, s1, 0, 0, 0); \
    } \
}

// exp2 + lane-local l + pack P frags for one tile
#define SOFTMAX(sc0v, sc1v, pf0v, pf1v) { \
    _Pragma("unroll") \
    for (int m = 0; m < 4; ++m) { \
        float a0 = fexp2(sc0v[m][0]), a1 = fexp2(sc0v[m][1]); \
        float a2 = fexp2(sc0v[m][2]), a3 = fexp2(sc0v[m][3]); \
        l0 += (a0 + a1) + (a2 + a3); \
        pf0v[m] = pack_pk(a0, a1, a2, a3); \
        float b0 = fexp2(sc1v[m][0]), b1 = fexp2(sc1v[m][1]); \
        float b2 = fexp2(sc1v[m][2]), b3 = fexp2(sc1v[m][3]); \
        l1 += (b0 + b1) + (b2 + b3); \
        pf1v[m] = pack_pk(b0, b1, b2, b3); \
    } \
}

// PV phase for one tile
#define PV(sVT, pf0v, pf1v) { \
    _Pragma("unroll") \
    for (int g = 0; g < 2; ++g) { \
        f16x8 a0 = cat_f16x8(pf0v[2 * g], pf0v[2 * g + 1]); \
        f16x8 a1 = cat_f16x8(pf1v[2 * g], pf1v[2 * g + 1]); \
        _Pragma("unroll") \
        for (int dg = 0; dg < 4; ++dg) { \
            f16x8 vf = *(const f16x8*)&(sVT)[(dg * 16 + l16) * 64 + \
                                             (((4 * g + quad) ^ sw) * 8)]; \
            oa0[dg] = __builtin_amdgcn_mfma_f32_16x16x32_f16(a0, vf, oa0[dg], 0, 0, 0); \
            oa1[dg] = __builtin_amdgcn_mfma_f32_16x16x32_f16(a1, vf, oa1[dg], 0, 0, 0); \
        } \
    } \
}

    STAGE_ATT(0);
    STAGE_ATT(1);

    for (int kt = 0; kt < 32; kt += 2) {
        if (kt + 2 < 32) {
            STAGE_ATT(kt + 2);
            STAGE_ATT(kt + 3);
            asm volatile("s_waitcnt vmcnt(8)" ::: "memory");   // pair kt,kt+1 landed
        } else {
            asm volatile("s_waitcnt vmcnt(0)" ::: "memory");
        }
        __builtin_amdgcn_s_barrier();

        const _Float16* sKa  = smem + (kt & 3) * SLOT;
        const _Float16* sVTa = sKa + 4096;
        const _Float16* sKb  = smem + ((kt + 1) & 3) * SLOT;
        const _Float16* sVTb = sKb + 4096;

        f32x4 sc0a[4], sc1a[4], sc0b[4], sc1b[4];
        f16x4 pf0a[4], pf1a[4], pf0b[4], pf1b[4];

        __builtin_amdgcn_s_setprio(1);
        QK(sKa, sc0a, sc1a);
        QK(sKb, sc0b, sc1b);
        __builtin_amdgcn_s_setprio(0);

        SOFTMAX(sc0a, sc1a, pf0a, pf1a);

        __builtin_amdgcn_s_setprio(1);
        PV(sVTa, pf0a, pf1a);
        SOFTMAX(sc0b, sc1b, pf0b, pf1b);
        PV(sVTb, pf0b, pf1b);
        __builtin_amdgcn_s_setprio(0);
    }
#undef STAGE_ATT
#undef QK
#undef SOFTMAX
#undef PV

    // epilogue: reduce l across quads, normalize, store fp16 O [t][1024]
    const int b = bh >> 4, h = bh & 15;
    for (int g = 0; g < 2; ++g) {
        float lr = (g == 0) ? l0 : l1;
        lr += __shfl_xor(lr, 16);
        lr += __shfl_xor(lr, 32);           // every lane: l(q = its l16) for group g
        float linv[4];
        for (int r = 0; r < 4; ++r)
            linv[r] = 1.f / __shfl(lr, quad * 4 + r);  // l for q = quad*4+r
        f32x4* oa = (g == 0) ? oa0 : oa1;
        long t0 = (long)b * S + qt * 128 + wave * 32 + g * 16;
        for (int dg = 0; dg < 4; ++dg) {
            int col = h * 64 + dg * 16 + l16;
            for (int r = 0; r < 4; ++r) {
                long idx = (t0 + quad * 4 + r) * 1024 + col;
                ob[idx] = (_Float16)(oa[dg][r] * linv[r]);
            }
        }
    }
}

// ---------- launch ----------
extern "C" void kernel_launch(void* const* d_in, const int* in_sizes, int n_in,
                              void* d_out, int out_size, void* d_ws, size_t ws_size,
                              hipStream_t stream)
{
    const float* x  = (const float*)d_in[0];
    // d_in[1] = e (unused by reference)
    const float* wq = (const float*)d_in[2];
    const float* wk = (const float*)d_in[3];
    const float* wv = (const float*)d_in[4];
    const float* wo = (const float*)d_in[5];
    float* out = (float*)d_out;

    const size_t MT = 4096UL * 1024UL;
    const size_t WT = 1024UL * 1024UL;
    _Float16* xh    = (_Float16*)d_ws;  // [4096][1024]
    _Float16* wqkvh = xh + MT;          // [3072][1024]
    _Float16* woh   = wqkvh + 3 * WT;   // [1024][1024]
    _Float16* qbuf  = woh + WT;         // [32][2048][64] (pre-scaled by log2e/8)
    _Float16* kbuf  = qbuf + MT;        // [32][32][4096] K subtile blobs (attn image)
    _Float16* vbuf  = kbuf + MT;        // [32][32][4096] V subtile blobs (attn image)
    _Float16* obuf  = vbuf + MT;        // [4096][1024]
    // total 24M halves = 48 MB of workspace

    cvt_all_kernel<<<8192, 256, 0, stream>>>(x, wq, wk, wv, wo, xh, wqkvh, woh);

    gemm128_qkv<<<dim3(32, 24), 128, 0, stream>>>(xh, wqkvh, qbuf, kbuf, vbuf);
    attn_kernel<<<512, 256, 0, stream>>>(qbuf, kbuf, vbuf, obuf);
    gemm128_out<<<dim3(32, 8), 256, 0, stream>>>(obuf, woh, out);
}

// Round 15
// 175.141 us; speedup vs baseline: 1.0348x; 1.0234x over previous
//
#include <hip/hip_runtime.h>

// ---------- types ----------
typedef _Float16 f16x8 __attribute__((ext_vector_type(8)));
typedef _Float16 f16x4 __attribute__((ext_vector_type(4)));
typedef _Float16 f16x2 __attribute__((ext_vector_type(2)));
typedef float f32x4 __attribute__((ext_vector_type(4)));
typedef unsigned int u32x4 __attribute__((ext_vector_type(4)));

// rho: global key row -> permuted row within 128-row K-tile (32-key groups kept)
#define RHO(s) (((s) & ~31) | (((s) >> 2) & 1) * 16 | (((s) >> 3) & 3) * 4 | ((s) & 3))

__device__ __forceinline__ float fexp2(float x) {
#if __has_builtin(__builtin_amdgcn_exp2f)
    return __builtin_amdgcn_exp2f(x);
#else
    return exp2f(x);
#endif
}
__device__ __forceinline__ f16x4 pack_f16x4(float a, float b, float c, float d) {
    f16x4 r;
    r[0] = (_Float16)a; r[1] = (_Float16)b;
    r[2] = (_Float16)c; r[3] = (_Float16)d;
    return r;
}
// packed RTZ convert: 2 floats -> 2 halves in one VALU op (P-matrix only)
__device__ __forceinline__ f16x4 pack_pk(float a, float b, float c, float d) {
#if __has_builtin(__builtin_amdgcn_cvt_pkrtz)
    f16x2 lo = __builtin_bit_cast(f16x2, __builtin_amdgcn_cvt_pkrtz(a, b));
    f16x2 hi = __builtin_bit_cast(f16x2, __builtin_amdgcn_cvt_pkrtz(c, d));
    f16x4 r;
    r[0] = lo[0]; r[1] = lo[1]; r[2] = hi[0]; r[3] = hi[1];
    return r;
#else
    return pack_f16x4(a, b, c, d);
#endif
}
__device__ __forceinline__ f16x8 cat_f16x8(f16x4 a, f16x4 b) {
    f16x8 r;
    for (int i = 0; i < 4; ++i) { r[i] = a[i]; r[4 + i] = b[i]; }
    return r;
}

// async global->LDS, 16B per lane; lds dest = wave-uniform base + lane*16
__device__ __forceinline__ void gld16(const void* g, void* l) {
#if __has_builtin(__builtin_amdgcn_global_load_lds)
    __builtin_amdgcn_global_load_lds(
        (const __attribute__((address_space(1))) void*)(unsigned long long)g,
        (__attribute__((address_space(3))) void*)(unsigned int)(unsigned long long)l,
        16, 0, 0);
#else
    *(u32x4*)l = *(const u32x4*)g;
#endif
}

// ---------- convert f32 -> fp16 (x + 4 weights in one launch) ----------
__global__ __launch_bounds__(256) void cvt_all_kernel(
    const float* __restrict__ x, const float* __restrict__ wq,
    const float* __restrict__ wk, const float* __restrict__ wv,
    const float* __restrict__ wo,
    _Float16* __restrict__ xh, _Float16* __restrict__ wqkvh,
    _Float16* __restrict__ woh)
{
    long i = (long)blockIdx.x * 256 + threadIdx.x;  // float4 index, 2M total
    const float* src; _Float16* dst; long off;
    if (i < 1048576)      { src = x;  dst = xh;              off = i; }
    else if (i < 1310720) { src = wq; dst = wqkvh;           off = i - 1048576; }
    else if (i < 1572864) { src = wk; dst = wqkvh + 1048576; off = i - 1310720; }
    else if (i < 1835008) { src = wv; dst = wqkvh + 2097152; off = i - 1572864; }
    else                  { src = wo; dst = woh;             off = i - 1835008; }
    float4 v = ((const float4*)src)[off];
    *(f16x4*)&dst[off * 4] = pack_f16x4(v.x, v.y, v.z, v.w);
}

// ---------- QKV GEMM: C = A @ B^T, 128x128 tile, BK=32, ring-4 LDS pipeline ----
// (R11 best-total config.) 256 threads (4 waves, 2Mx2N, acc[4][4]), ring-4 =
// 64 KB -> 2 blocks/CU; grid 32x24=768. Counted vmcnt(8). T2 slot-swizzle.
// Step-1 + stage-depth-2 ring-slot safety: stage slot (t+2)&3 (and the skewed
// (t+3)&3/(t+4)&3) never aliases a slot being read at <=1-iter barrier skew.
// Epilogue: Q -> qb [bh][s][64] (pre-scaled log2e/8); K -> kb attn-image blobs;
// V -> vb 64-key subtile blobs (subtile = kt0*2 + wm).
__global__ __launch_bounds__(256, 2) void gemm128_qkv(
    const _Float16* __restrict__ A, const _Float16* __restrict__ B,
    _Float16* __restrict__ qb, _Float16* __restrict__ kb2,
    _Float16* __restrict__ vb)
{
    constexpr int K = 1024;
    constexpr int NT = 32;  // K / 32
    __shared__ __align__(16) _Float16 smem[4 * 8192];  // 64 KB ring

    const int tid = threadIdx.x;
    const int wave = tid >> 6, lane = tid & 63;
    const int quad = lane >> 4, l16 = lane & 15;
    const int bm = blockIdx.x, bn = blockIdx.y;
    const int wm = wave >> 1;  // 0..1 : M half (64 rows)
    const int wn = wave & 1;   // 0..1 : N half (64 cols)

    const int arow0 = bm * 128, brow0 = bn * 128;

    const int c0 = tid, c1 = 256 + tid;
    const int r0 = c0 >> 2, k80 = ((c0 & 3) ^ ((c0 >> 3) & 3)) * 8;
    const int r1 = c1 >> 2, k81 = ((c1 & 3) ^ ((c1 >> 3) & 3)) * 8;
    const int rsw = (l16 >> 1) & 3;  // read-side slot mask (row terms 0 mod 4)

    f32x4 zero = {0.f, 0.f, 0.f, 0.f};
    f32x4 acc[4][4];
    for (int i = 0; i < 4; i++) for (int j = 0; j < 4; j++) acc[i][j] = zero;

#define STAGE(t) { \
    _Float16* sA_ = smem + ((t) & 3) * 8192; \
    _Float16* sB_ = sA_ + 4096; \
    const _Float16* ga_ = A + (long)arow0 * K + (t) * 32; \
    const _Float16* gb_ = B + (long)brow0 * K + (t) * 32; \
    gld16(&ga_[(long)r0 * K + k80], &sA_[c0 * 8]); \
    gld16(&ga_[(long)r1 * K + k81], &sA_[c1 * 8]); \
    gld16(&gb_[(long)r0 * K + k80], &sB_[c0 * 8]); \
    gld16(&gb_[(long)r1 * K + k81], &sB_[c1 * 8]); \
}

    STAGE(0);
    STAGE(1);

    for (int t = 0; t < NT; ++t) {
        if (t + 2 < NT) {
            STAGE(t + 2);
            asm volatile("s_waitcnt vmcnt(8)" ::: "memory");   // tile t landed
        } else if (t + 1 < NT) {
            asm volatile("s_waitcnt vmcnt(4)" ::: "memory");   // tile t landed
        } else {
            asm volatile("s_waitcnt vmcnt(0)" ::: "memory");
        }
        __builtin_amdgcn_s_barrier();

        const _Float16* sA = smem + (t & 3) * 8192;
        const _Float16* sB = sA + 4096;
        f16x8 af[4], bf[4];
#pragma unroll
        for (int n = 0; n < 4; ++n)
            bf[n] = *(const f16x8*)&sB[(wn * 64 + n * 16 + l16) * 32 +
                                       ((quad ^ rsw) * 8)];
#pragma unroll
        for (int m = 0; m < 4; ++m)
            af[m] = *(const f16x8*)&sA[(wm * 64 + m * 16 + l16) * 32 +
                                       ((quad ^ rsw) * 8)];
        __builtin_amdgcn_s_setprio(1);
#pragma unroll
        for (int m = 0; m < 4; ++m)
#pragma unroll
            for (int n = 0; n < 4; ++n)
                acc[m][n] = __builtin_amdgcn_mfma_f32_16x16x32_f16(af[m], bf[n], acc[m][n], 0, 0, 0);
        __builtin_amdgcn_s_setprio(0);
    }
#undef STAGE

    // ---- epilogue ----
    const int p = bn >> 3;
    const int h = (bn & 7) * 2 + wn;
    const int b = bm >> 4;
    const int kt0 = bm & 15;
    const float QSCALE = 0.18033688011112042f;  // log2(e)/8 -> exp2-domain softmax

    if (p == 0) {
        const long base = ((long)(b * 16 + h)) * 2048;
        for (int m = 0; m < 4; ++m) {
            for (int n = 0; n < 4; ++n) {
                int dd = n * 16 + l16;
                for (int r = 0; r < 4; ++r) {
                    long s = kt0 * 128 + wm * 64 + m * 16 + quad * 4 + r;
                    qb[(base + s) * 64 + dd] = (_Float16)(acc[m][n][r] * QSCALE);
                }
            }
        }
    } else if (p == 1) {
        _Float16* dstt = kb2 + ((long)(b * 16 + h) * 16 + kt0) * 8192;
        for (int m = 0; m < 4; ++m) {
            for (int n = 0; n < 4; ++n) {
                int dd = n * 16 + l16;
                int ch = dd >> 3, dl = dd & 7;
                for (int r = 0; r < 4; ++r) {
                    int rk = wm * 64 + m * 16 + quad * 4 + r;
                    int pr = RHO(rk);
                    dstt[pr * 64 + ((ch ^ (pr & 7)) << 3) + dl] = (_Float16)acc[m][n][r];
                }
            }
        }
    } else {
        // V 64-key subtile image: subtile = kt0*2 + wm
        _Float16* dstt = vb + (((long)(b * 16 + h) * 16 + kt0) * 2 + wm) * 4096;
        for (int m = 0; m < 4; ++m) {
            int c0v = m * 16 + quad * 4;  // key col within the 64-key subtile
            for (int n = 0; n < 4; ++n) {
                int dd = n * 16 + l16;
                int voff = dd * 64 + (((c0v >> 3) ^ (dd & 7)) << 3) + (c0v & 7);
                *(f16x4*)&dstt[voff] = pack_f16x4(acc[m][n][0], acc[m][n][1],
                                                  acc[m][n][2], acc[m][n][3]);
            }
        }
    }
}

// ---------- out-proj GEMM: C = A @ B^T, 128x128 tile, BK=32, ring-4, fp32 out ----
__global__ __launch_bounds__(256, 2) void gemm128_out(
    const _Float16* __restrict__ A, const _Float16* __restrict__ B,
    float* __restrict__ outf)
{
    constexpr int K = 1024;
    constexpr int NT = 32;  // K / 32
    __shared__ __align__(16) _Float16 smem[4 * 8192];  // 64 KB ring

    const int tid = threadIdx.x;
    const int wave = tid >> 6, lane = tid & 63;
    const int quad = lane >> 4, l16 = lane & 15;
    const int bm = blockIdx.x, bn = blockIdx.y;
    const int wm = wave >> 1;
    const int wn = wave & 1;

    const int arow0 = bm * 128, brow0 = bn * 128;

    const int c0 = tid, c1 = 256 + tid;
    const int r0 = c0 >> 2, k80 = ((c0 & 3) ^ ((c0 >> 3) & 3)) * 8;
    const int r1 = c1 >> 2, k81 = ((c1 & 3) ^ ((c1 >> 3) & 3)) * 8;
    const int rsw = (l16 >> 1) & 3;

    f32x4 zero = {0.f, 0.f, 0.f, 0.f};
    f32x4 acc[4][4];
    for (int i = 0; i < 4; i++) for (int j = 0; j < 4; j++) acc[i][j] = zero;

#define STAGE(t) { \
    _Float16* sA_ = smem + ((t) & 3) * 8192; \
    _Float16* sB_ = sA_ + 4096; \
    const _Float16* ga_ = A + (long)arow0 * K + (t) * 32; \
    const _Float16* gb_ = B + (long)brow0 * K + (t) * 32; \
    gld16(&ga_[(long)r0 * K + k80], &sA_[c0 * 8]); \
    gld16(&ga_[(long)r1 * K + k81], &sA_[c1 * 8]); \
    gld16(&gb_[(long)r0 * K + k80], &sB_[c0 * 8]); \
    gld16(&gb_[(long)r1 * K + k81], &sB_[c1 * 8]); \
}

    STAGE(0);
    STAGE(1);

    for (int t = 0; t < NT; ++t) {
        if (t + 2 < NT) {
            STAGE(t + 2);
            asm volatile("s_waitcnt vmcnt(8)" ::: "memory");
        } else if (t + 1 < NT) {
            asm volatile("s_waitcnt vmcnt(4)" ::: "memory");
        } else {
            asm volatile("s_waitcnt vmcnt(0)" ::: "memory");
        }
        __builtin_amdgcn_s_barrier();

        const _Float16* sA = smem + (t & 3) * 8192;
        const _Float16* sB = sA + 4096;
        f16x8 af[4], bf[4];
#pragma unroll
        for (int n = 0; n < 4; ++n)
            bf[n] = *(const f16x8*)&sB[(wn * 64 + n * 16 + l16) * 32 +
                                       ((quad ^ rsw) * 8)];
#pragma unroll
        for (int m = 0; m < 4; ++m)
            af[m] = *(const f16x8*)&sA[(wm * 64 + m * 16 + l16) * 32 +
                                       ((quad ^ rsw) * 8)];
        __builtin_amdgcn_s_setprio(1);
#pragma unroll
        for (int m = 0; m < 4; ++m)
#pragma unroll
            for (int n = 0; n < 4; ++n)
                acc[m][n] = __builtin_amdgcn_mfma_f32_16x16x32_f16(af[m], bf[n], acc[m][n], 0, 0, 0);
        __builtin_amdgcn_s_setprio(0);
    }
#undef STAGE

    for (int m = 0; m < 4; ++m) {
        int row = bm * 128 + wm * 64 + m * 16 + quad * 4;
        for (int n = 0; n < 4; ++n) {
            int col = bn * 128 + wn * 64 + n * 16 + l16;
            for (int r = 0; r < 4; ++r)
                outf[(long)(row + r) * 1024 + col] = acc[m][n][r];
        }
    }
}

// ---------- flash attention v17b: 256 q rows/block, RACE-FIXED stage placement --
// R14's failure: staging BEFORE the barrier in a step-2 pair loop lets a lead
// wave stage slot (kt+4)&3 == kt&3 while a lagging wave still reads it (step-1
// GEMM rings are immune; step-2 advances the ring 2 slots/barrier). Fix: stage
// AFTER the barrier -- slots (kt+2)&3,(kt+3)&3 were last read in iter kt-2,
// finished by every wave before barrier(kt), so no alias at any skew.
// vmcnt(0) before the barrier is ~free: the only outstanding loads (tiles
// kt,kt+1) were issued a full pair-iteration earlier.
// Geometry: 256 q rows (512 thr, 8 waves), grid 256 = 1 block/CU -> K/V staged
// once per CU per tile (half of v16). Pair-interleaved compute, ring-4 LDS.
// XCD-pinned decode: n&7 == bh&7.
__global__ __launch_bounds__(512, 2) void attn_kernel(
    const _Float16* __restrict__ qb, const _Float16* __restrict__ kb,
    const _Float16* __restrict__ vt, _Float16* __restrict__ ob)
{
    constexpr int S = 2048;
    constexpr int SLOT = 8192;                         // halves: K 4096 | V 4096
    __shared__ __align__(16) _Float16 smem[4 * SLOT];  // 64 KB ring

    const int tid = threadIdx.x, wave = tid >> 6, lane = tid & 63;
    const int quad = lane >> 4, l16 = lane & 15;
    const int sw = l16 & 7;
    // XCD-pinned decode: qt = (n>>3)&7 (256-row tiles), bh = (n&7) | ((n>>6)<<3)
    const int n = blockIdx.x;
    const int qt = (n >> 3) & 7;
    const int bh = (n & 7) | ((n >> 6) << 3);

    // Q frags (B-operand of 16x16x32), two q-groups; wave owns rows wave*32..+31
    const _Float16* qrow = qb + (((long)bh * S) + qt * 256 + wave * 32 + l16) * 64;
    f16x8 qf00 = *(const f16x8*)&qrow[quad * 8];
    f16x8 qf01 = *(const f16x8*)&qrow[32 + quad * 8];
    f16x8 qf10 = *(const f16x8*)&qrow[16 * 64 + quad * 8];
    f16x8 qf11 = *(const f16x8*)&qrow[16 * 64 + 32 + quad * 8];

    const _Float16* kg = kb + (long)bh * 32 * 4096;  // 8 KB 64-key subtile blobs
    const _Float16* vg = vt + (long)bh * 32 * 4096;

    float l0 = 0.f, l1 = 0.f;
    f32x4 zero = {0.f, 0.f, 0.f, 0.f};
    f32x4 oa0[4], oa1[4];  // D[m=q=quad*4+r][n=d=l16], dg blocks of 16 d
    for (int d = 0; d < 4; d++) { oa0[d] = zero; oa1[d] = zero; }

    // linear blob -> linear LDS, 16 B/lane; 512 threads cover 512 chunks each of K,V
#define STAGE_ATT(t) { \
    const _Float16* gk_ = kg + (long)(t) * 4096; \
    const _Float16* gv_ = vg + (long)(t) * 4096; \
    _Float16* sk_ = smem + ((t) & 3) * SLOT; \
    _Float16* sv_ = sk_ + 4096; \
    gld16(&gk_[tid * 8], &sk_[tid * 8]); \
    gld16(&gv_[tid * 8], &sv_[tid * 8]); \
}

// QK phase for one tile: 8 chained-pair MFMAs -> sc0/sc1[4]
#define QK(sK, sc0v, sc1v) { \
    _Pragma("unroll") \
    for (int m = 0; m < 4; ++m) { \
        const _Float16* kr = &(sK)[(m * 16 + l16) * 64]; \
        f16x8 kf0 = *(const f16x8*)&kr[((quad)     ^ sw) * 8]; \
        f16x8 kf1 = *(const f16x8*)&kr[((quad + 4) ^ sw) * 8]; \
        f32x4 s0 = __builtin_amdgcn_mfma_f32_16x16x32_f16(kf0, qf00, zero, 0, 0, 0); \
        sc0v[m] = __builtin_amdgcn_mfma_f32_16x16x32_f16(kf1, qf01, s0, 0, 0, 0); \
        f32x4 s1 = __builtin_amdgcn_mfma_f32_16x16x32_f16(kf0, qf10, zero, 0, 0, 0); \
        sc1v[m] = __builtin_amdgcn_mfma_f32_16x16x32_f16(kf1, qf11, s1, 0, 0, 0); \
    } \
}

// exp2 + lane-local l + pack P frags for one tile
#define SOFTMAX(sc0v, sc1v, pf0v, pf1v) { \
    _Pragma("unroll") \
    for (int m = 0; m < 4; ++m) { \
        float a0 = fexp2(sc0v[m][0]), a1 = fexp2(sc0v[m][1]); \
        float a2 = fexp2(sc0v[m][2]), a3 = fexp2(sc0v[m][3]); \
        l0 += (a0 + a1) + (a2 + a3); \
        pf0v[m] = pack_pk(a0, a1, a2, a3); \
        float b0 = fexp2(sc1v[m][0]), b1 = fexp2(sc1v[m][1]); \
        float b2 = fexp2(sc1v[m][2]), b3 = fexp2(sc1v[m][3]); \
        l1 += (b0 + b1) + (b2 + b3); \
        pf1v[m] = pack_pk(b0, b1, b2, b3); \
    } \
}

// PV phase for one tile
#define PV(sVT, pf0v, pf1v) { \
    _Pragma("unroll") \
    for (int g = 0; g < 2; ++g) { \
        f16x8 a0 = cat_f16x8(pf0v[2 * g], pf0v[2 * g + 1]); \
        f16x8 a1 = cat_f16x8(pf1v[2 * g], pf1v[2 * g + 1]); \
        _Pragma("unroll") \
        for (int dg = 0; dg < 4; ++dg) { \
            f16x8 vf = *(const f16x8*)&(sVT)[(dg * 16 + l16) * 64 + \
                                             (((4 * g + quad) ^ sw) * 8)]; \
            oa0[dg] = __builtin_amdgcn_mfma_f32_16x16x32_f16(a0, vf, oa0[dg], 0, 0, 0); \
            oa1[dg] = __builtin_amdgcn_mfma_f32_16x16x32_f16(a1, vf, oa1[dg], 0, 0, 0); \
        } \
    } \
}

    STAGE_ATT(0);
    STAGE_ATT(1);

    for (int kt = 0; kt < 32; kt += 2) {
        // tiles kt,kt+1 are the only outstanding loads (issued last iter,
        // after the previous barrier) -> this drain is effectively free.
        asm volatile("s_waitcnt vmcnt(0)" ::: "memory");
        __builtin_amdgcn_s_barrier();

        // stage AFTER the barrier: slots (kt+2)&3,(kt+3)&3 were last read in
        // iter kt-2, which every wave finished before reaching this barrier.
        if (kt + 2 < 32) {
            STAGE_ATT(kt + 2);
            STAGE_ATT(kt + 3);
        }

        const _Float16* sKa  = smem + (kt & 3) * SLOT;
        const _Float16* sVTa = sKa + 4096;
        const _Float16* sKb  = smem + ((kt + 1) & 3) * SLOT;
        const _Float16* sVTb = sKb + 4096;

        f32x4 sc0a[4], sc1a[4], sc0b[4], sc1b[4];
        f16x4 pf0a[4], pf1a[4], pf0b[4], pf1b[4];

        __builtin_amdgcn_s_setprio(1);
        QK(sKa, sc0a, sc1a);
        QK(sKb, sc0b, sc1b);
        __builtin_amdgcn_s_setprio(0);

        SOFTMAX(sc0a, sc1a, pf0a, pf1a);

        __builtin_amdgcn_s_setprio(1);
        PV(sVTa, pf0a, pf1a);
        SOFTMAX(sc0b, sc1b, pf0b, pf1b);
        PV(sVTb, pf0b, pf1b);
        __builtin_amdgcn_s_setprio(0);
    }
#undef STAGE_ATT
#undef QK
#undef SOFTMAX
#undef PV

    // epilogue: reduce l across quads, normalize, store fp16 O [t][1024]
    const int b = bh >> 4, h = bh & 15;
    for (int g = 0; g < 2; ++g) {
        float lr = (g == 0) ? l0 : l1;
        lr += __shfl_xor(lr, 16);
        lr += __shfl_xor(lr, 32);           // every lane: l(q = its l16) for group g
        float linv[4];
        for (int r = 0; r < 4; ++r)
            linv[r] = 1.f / __shfl(lr, quad * 4 + r);  // l for q = quad*4+r
        f32x4* oa = (g == 0) ? oa0 : oa1;
        long t0 = (long)b * S + qt * 256 + wave * 32 + g * 16;
        for (int dg = 0; dg < 4; ++dg) {
            int col = h * 64 + dg * 16 + l16;
            for (int r = 0; r < 4; ++r) {
                long idx = (t0 + quad * 4 + r) * 1024 + col;
                ob[idx] = (_Float16)(oa[dg][r] * linv[r]);
            }
        }
    }
}

// ---------- launch ----------
extern "C" void kernel_launch(void* const* d_in, const int* in_sizes, int n_in,
                              void* d_out, int out_size, void* d_ws, size_t ws_size,
                              hipStream_t stream)
{
    const float* x  = (const float*)d_in[0];
    // d_in[1] = e (unused by reference)
    const float* wq = (const float*)d_in[2];
    const float* wk = (const float*)d_in[3];
    const float* wv = (const float*)d_in[4];
    const float* wo = (const float*)d_in[5];
    float* out = (float*)d_out;

    const size_t MT = 4096UL * 1024UL;
    const size_t WT = 1024UL * 1024UL;
    _Float16* xh    = (_Float16*)d_ws;  // [4096][1024]
    _Float16* wqkvh = xh + MT;          // [3072][1024]
    _Float16* woh   = wqkvh + 3 * WT;   // [1024][1024]
    _Float16* qbuf  = woh + WT;         // [32][2048][64] (pre-scaled by log2e/8)
    _Float16* kbuf  = qbuf + MT;        // [32][32][4096] K subtile blobs (attn image)
    _Float16* vbuf  = kbuf + MT;        // [32][32][4096] V subtile blobs (attn image)
    _Float16* obuf  = vbuf + MT;        // [4096][1024]
    // total 24M halves = 48 MB of workspace

    cvt_all_kernel<<<8192, 256, 0, stream>>>(x, wq, wk, wv, wo, xh, wqkvh, woh);

    gemm128_qkv<<<dim3(32, 24), 256, 0, stream>>>(xh, wqkvh, qbuf, kbuf, vbuf);
    attn_kernel<<<256, 512, 0, stream>>>(qbuf, kbuf, vbuf, obuf);
    gemm128_out<<<dim3(32, 8), 256, 0, stream>>>(obuf, woh, out);
}